// Round 1
// baseline (129.560 us; speedup 1.0000x reference)
//
#include <hip/hip_runtime.h>
#include <cstdint>

// Radius NMS: B=4, C=4 (classes 1..3), N = 8192. Output: kept_coords
// [4,3,8192,2] f32 then keep [4,3,8192] f32, flat.
//
// One 512-thread workgroup per (batch,class) problem; 12 blocks.
// Phase 1: argmax -> valid; stable block-scan compaction into LDS (float2),
//          candidate coords + flags kept in REGISTERS for phase 3.
// Phase 2: single-wave tiled greedy NMS, software-pipelined at distance 1,
//   with a spatial hash storing KEPT COORDINATES directly (no indirection):
//   - grid 56x56, cell 4.2 m over [-117.6,117.6) with clamped indices.
//     Kept points pairwise >3 m apart => <=4 per cell (2x2 subsquares of
//     side 2.1, diagonal 2.97 < 3). Clamping is monotone, so any pair
//     within 3 m still maps to adjacent/equal cells -> pruning SOUND;
//     exact d^2<=9 decides suppression.
//   - per 64-pt tile t: PREFETCH tile t+1 (coords + 18 ds_read_b128 of the
//     9 neighbor cells' 4 float2 slots) BEFORE the serial resolve of tile t.
//     The prefetched grid state misses tile t's kept points; those are
//     compensated during the resolve: each broadcast kept point (xl,yl)
//     also accumulates supB |= d2(B,l)<=9 (off the critical ballot chain).
//     Grid-read latency + check-VALU thus hide under the resolve chain.
//   - kept lanes insert their own coords into the grid (packed-byte LDS
//     atomicAdd alloc). NO barriers in the tile loop (single wave).
// Phase 3: each thread scatters its own points from registers via its
//   phase-1 rank and the keptW bitmask.
//
// Numerics: fp contract OFF so dx*dx+dy*dy matches numpy (no FMA); argmax
// uses strict > (first-max tie-break like jnp.argmax). absmax=0 previously.

#define NPTS 8192
#define CAP  2304          // candidates; M ~ Binom(8192,1/4) = 2048 +/- 39 (6.5 sigma)
#define R2C  9.0f
#define GW   56            // grid cells per dim
#define GORG 117.6f        // grid covers [-117.6, 117.6), clamped beyond (3.92 sigma)
#define GINV 0.23809524f   // 1/4.2
#define GMAXC 55.0f
#define SENT 3.0e37f       // sentinel coord: d2 vs any real point is huge

__global__ __launch_bounds__(512) void radius_nms_kernel(
    const float* __restrict__ seg,    // [4,4,8192]
    const float* __restrict__ lidar,  // [4,5,8192]
    float* __restrict__ out)          // 294912 floats
{
#pragma clang fp contract(off)
    const int bx   = blockIdx.x;   // 0..11
    const int b    = bx / 3;
    const int cls  = (bx % 3) + 1;
    const int tid  = threadIdx.x;
    const int lane = tid & 63;
    const int wv   = tid >> 6;     // 0..7

    __shared__ float2 xy[CAP];                       // candidate coords
    __shared__ unsigned long long keptW[CAP / 64];   // keep bits per tile
    __shared__ int waveTot[8];
    __shared__ float4 gslot4[GW * GW * 2];           // 4 float2 slots/cell, sentinel
    __shared__ unsigned int cnt32[(GW * GW + 3) / 4];// packed u8 counts

    float* out0 = out + (size_t)bx * NPTS * 2;
    float* out1 = out + 196608 + (size_t)bx * NPTS;

    // ---- zero outputs (harness poisons d_out) + init grid ----
    const float4 z4 = make_float4(0.f, 0.f, 0.f, 0.f);
    float4* o04 = (float4*)out0;
    float4* o14 = (float4*)out1;
    for (int i = tid; i < NPTS / 2; i += 512) o04[i] = z4;   // 16384 floats
    for (int i = tid; i < NPTS / 4; i += 512) o14[i] = z4;   // 8192 floats
    const float4 s4 = make_float4(SENT, SENT, SENT, SENT);
    for (int i = tid; i < GW * GW * 2; i += 512) gslot4[i] = s4;
    for (int i = tid; i < (GW * GW + 3) / 4; i += 512) cnt32[i] = 0u;

    // ---- phase 1: argmax + valid flags (16 contiguous points / thread) ----
    const float* segb = seg + (size_t)b * 4 * NPTS;
    const float* lx   = lidar + (size_t)b * 5 * NPTS;
    const float* ly   = lx + NPTS;

    float px[16], py[16];
    int flags = 0, cnt = 0;
    const int n0 = tid * 16;
#pragma unroll
    for (int k = 0; k < 16; ++k) {
        const int n = n0 + k;
        float v0 = segb[n];
        float v1 = segb[NPTS + n];
        float v2 = segb[2 * NPTS + n];
        float v3 = segb[3 * NPTS + n];
        int bi = 0; float bv = v0;
        if (v1 > bv) { bv = v1; bi = 1; }
        if (v2 > bv) { bv = v2; bi = 2; }
        if (v3 > bv) { bv = v3; bi = 3; }
        px[k] = lx[n];
        py[k] = ly[n];
        if (bi == cls) { flags |= (1 << k); ++cnt; }
    }

    // ---- stable block scan of per-thread counts ----
    int v = cnt;
    for (int off = 1; off < 64; off <<= 1) {
        int nv = __shfl_up(v, off, 64);
        if (lane >= off) v += nv;
    }
    if (lane == 63) waveTot[wv] = v;
    __syncthreads();
    if (wv == 0) {
        int t = (lane < 8) ? waveTot[lane] : 0;
        for (int off = 1; off < 8; off <<= 1) {
            int nt = __shfl_up(t, off, 64);
            if (lane >= off) t += nt;
        }
        if (lane < 8) waveTot[lane] = t;
    }
    __syncthreads();

    int M = waveTot[7];
    if (M > CAP) M = CAP;
    const int rank0 = ((wv == 0) ? 0 : waveTot[wv - 1]) + v - cnt;
    int base = rank0;
#pragma unroll
    for (int k = 0; k < 16; ++k) {
        if (flags & (1 << k)) {
            if (base < CAP) xy[base] = make_float2(px[k], py[k]);
            ++base;
        }
    }
    __syncthreads();

    // ---- phase 2: single-wave pipelined greedy NMS with coord-grid ----
    if (wv == 0) {
        const int ntiles = (M + 63) >> 6;
        float2* g2 = (float2*)gslot4;

        // prologue: tile 0 (grid empty -> supA = false)
        float qxA = 3.0e38f, qyA = 3.0e38f;
        if (lane < M) { float2 q = xy[lane]; qxA = q.x; qyA = q.y; }
        float fa = floorf((qxA + GORG) * GINV);
        fa = fminf(fmaxf(fa, 0.0f), GMAXC);
        float fb = floorf((qyA + GORG) * GINV);
        fb = fminf(fmaxf(fb, 0.0f), GMAXC);
        int cA = (int)fb * GW + (int)fa;
        bool supA = false;

        for (int t = 0; t < ntiles; ++t) {
            const int ts = t << 6;

            // -- prefetch tile t+1: coords, cell, 18 b128 slot reads --
            float qxB = 3.0e38f, qyB = 3.0e38f;
            {
                const int p2 = ts + 64 + lane;
                if (p2 < M) { float2 q = xy[p2]; qxB = q.x; qyB = q.y; }
            }
            float fx = floorf((qxB + GORG) * GINV);
            fx = fminf(fmaxf(fx, 0.0f), GMAXC);
            float fy = floorf((qyB + GORG) * GINV);
            fy = fminf(fmaxf(fy, 0.0f), GMAXC);
            const int cxB = (int)fx, cyB = (int)fy;
            const int cB  = cyB * GW + cxB;
            const int cxm = (cxB > 0) ? cxB - 1 : 0;
            const int cxp = (cxB < GW - 1) ? cxB + 1 : GW - 1;
            const int rm  = ((cyB > 0) ? cyB - 1 : 0) * GW;
            const int r0  = cyB * GW;
            const int rp  = ((cyB < GW - 1) ? cyB + 1 : GW - 1) * GW;
            const int cells[9] = { rm + cxm, rm + cxB, rm + cxp,
                                   r0 + cxm, r0 + cxB, r0 + cxp,
                                   rp + cxm, rp + cxB, rp + cxp };
            float4 sv[18];
#pragma unroll
            for (int i = 0; i < 9; ++i) {
                sv[2 * i]     = gslot4[2 * cells[i]];
                sv[2 * i + 1] = gslot4[2 * cells[i] + 1];
            }

            // -- serial greedy resolve of tile t (+ compensation for t+1) --
            int cntT = M - ts; if (cntT > 64) cntT = 64;
            const unsigned long long tm =
                (cntT >= 64) ? ~0ull : ((1ull << cntT) - 1ull);
            unsigned long long alive = __ballot(!supA) & tm;
            unsigned long long keepm = 0ull;
            bool supB2 = false;
            while (alive) {
                const int l = __builtin_ctzll(alive);
                const float xl = __int_as_float(
                    __builtin_amdgcn_readlane(__float_as_int(qxA), l));
                const float yl = __int_as_float(
                    __builtin_amdgcn_readlane(__float_as_int(qyA), l));
                const float dxA = qxA - xl;
                const float dyA = qyA - yl;
                unsigned long long b2 = __ballot((dxA * dxA + dyA * dyA) <= R2C);
                const float dxB = qxB - xl;            // off-chain: compensates
                const float dyB = qyB - yl;            // tile t's kept for t+1
                supB2 = supB2 | ((dxB * dxB + dyB * dyB) <= R2C);
                keepm |= (1ull << l);
                alive &= ~b2;   // clears l (d2=0) and in-radius later points
            }
            if (lane == 0) keptW[t] = keepm;

            // -- insert kept points (own coords) into grid --
            if ((keepm >> lane) & 1ull) {
                const unsigned sh = 8u * (unsigned)(cA & 3);
                unsigned old = atomicAdd(&cnt32[cA >> 2], 1u << sh);
                unsigned mc = (old >> sh) & 0xFFu;
                if (mc < 4u) g2[cA * 4 + (int)mc] = make_float2(qxA, qyA);
            }

            // -- finish tile t+1's hash check from prefetched slots --
            bool sup = supB2;
#pragma unroll
            for (int i = 0; i < 9; ++i) {
                const float4 a = sv[2 * i];
                const float4 c = sv[2 * i + 1];
                float dx, dy;
                dx = qxB - a.x; dy = qyB - a.y; sup |= (dx * dx + dy * dy) <= R2C;
                dx = qxB - a.z; dy = qyB - a.w; sup |= (dx * dx + dy * dy) <= R2C;
                dx = qxB - c.x; dy = qyB - c.y; sup |= (dx * dx + dy * dy) <= R2C;
                dx = qxB - c.z; dy = qyB - c.w; sup |= (dx * dx + dy * dy) <= R2C;
            }
            supA = sup; qxA = qxB; qyA = qyB; cA = cB;
        }
    }
    __syncthreads();

    // ---- phase 3: scatter own kept points from registers ----
    int j = rank0;
#pragma unroll
    for (int k = 0; k < 16; ++k) {
        if (flags & (1 << k)) {
            if (j < M && ((keptW[j >> 6] >> (j & 63)) & 1ull)) {
                const int n = n0 + k;
                out0[2 * n]     = px[k];
                out0[2 * n + 1] = py[k];
                out1[n]         = 1.0f;
            }
            ++j;
        }
    }
}

extern "C" void kernel_launch(void* const* d_in, const int* in_sizes, int n_in,
                              void* d_out, int out_size, void* d_ws, size_t ws_size,
                              hipStream_t stream) {
    const float* seg   = (const float*)d_in[0];   // [4,4,64,128] f32
    const float* lidar = (const float*)d_in[1];   // [4,5,64,128] f32
    float* out = (float*)d_out;
    radius_nms_kernel<<<dim3(12), dim3(512), 0, stream>>>(seg, lidar, out);
}

// Round 2
// 122.104 us; speedup vs baseline: 1.0611x; 1.0611x over previous
//
#include <hip/hip_runtime.h>
#include <cstdint>

// Radius NMS: B=4, C=4 (classes 1..3), N = 8192. Output: kept_coords
// [4,3,8192,2] f32 then keep [4,3,8192] f32, flat.
//
// One 1024-thread workgroup per (batch,class) problem; 12 blocks.
// Phase 1: argmax -> valid; stable block-scan compaction into LDS (float2)
//          + PRECOMPUTED packed cell index (cy<<8|cx) per candidate.
//          Candidate coords + flags stay in REGISTERS for phase 3.
// Phase 2: single-wave tiled greedy NMS with a coordinate spatial hash:
//   - grid 56x56, cell 4.2 m over [-117.6,117.6) with clamped indices.
//     Kept points pairwise >3 m apart => <=4 per cell (2x2 subsquares of
//     side 2.1, diagonal 2.97 < 3). Clamping is monotone, so any pair
//     within 3 m still maps to adjacent/equal cells -> pruning SOUND;
//     exact d^2<=9 decides suppression. Slots hold COORDS (float2,
//     sentinel-filled) -> no second dependent indirection round.
//   - per 64-pt tile: next tile's coords+cell prefetched (2 small LDS
//     reads, independent of this tile's work), 36 scattered ds_read_b64
//     slot reads (b64 = conflict-cheap width; b128 measured 7.6x worse
//     conflict-cy/access in R1), fminf/min3 tree combine, lean serial
//     readlane-broadcast greedy resolve (NO extra in-loop VALU -- R1
//     showed in-order single-wave has no free "off-chain" slots), then
//     kept lanes insert their coords (packed-byte LDS atomicAdd alloc).
//     NO barriers in the tile loop (single wave, wave-synchronous).
// Phase 3: each thread scatters its own points from registers via its
//   phase-1 rank and the keptW bitmask.
//
// Numerics: fp contract OFF so dx*dx+dy*dy matches numpy (no FMA); argmax
// uses strict > (first-max tie-break like jnp.argmax). absmax=0 in R0/R1.

#define NPTS 8192
#define CAP  2304          // candidates; M ~ Binom(8192,1/4) = 2048 +/- 39 (6.5 sigma)
#define R2C  9.0f
#define GW   56            // grid cells per dim
#define GORG 117.6f        // grid covers [-117.6, 117.6), clamped beyond (3.92 sigma)
#define GINV 0.23809524f   // 1/4.2
#define GMAXC 55.0f
#define SENT 3.0e37f       // sentinel slot coord: d2 vs any real point = inf

__global__ __launch_bounds__(1024) void radius_nms_kernel(
    const float* __restrict__ seg,    // [4,4,8192]
    const float* __restrict__ lidar,  // [4,5,8192]
    float* __restrict__ out)          // 294912 floats
{
#pragma clang fp contract(off)
    const int bx   = blockIdx.x;   // 0..11
    const int b    = bx / 3;
    const int cls  = (bx % 3) + 1;
    const int tid  = threadIdx.x;
    const int lane = tid & 63;
    const int wv   = tid >> 6;     // 0..15

    __shared__ float2 xy[CAP];                       // candidate coords
    __shared__ unsigned short cellA[CAP];            // packed (cy<<8)|cx
    __shared__ unsigned long long keptW[CAP / 64];   // keep bits per tile
    __shared__ int waveTot[16];
    __shared__ float2 gslot[GW * GW * 4];            // 4 coord slots/cell
    __shared__ unsigned int cnt32[(GW * GW + 3) / 4];// packed u8 counts

    float* out0 = out + (size_t)bx * NPTS * 2;
    float* out1 = out + 196608 + (size_t)bx * NPTS;

    // ---- zero outputs (harness poisons d_out) + init grid ----
    const float4 z4 = make_float4(0.f, 0.f, 0.f, 0.f);
    float4* o04 = (float4*)out0;
    float4* o14 = (float4*)out1;
    for (int i = tid; i < NPTS / 2; i += 1024) o04[i] = z4;   // 16384 floats
    for (int i = tid; i < NPTS / 4; i += 1024) o14[i] = z4;   // 8192 floats
    const float2 s2 = make_float2(SENT, SENT);
    for (int i = tid; i < GW * GW * 4; i += 1024) gslot[i] = s2;
    for (int i = tid; i < (GW * GW + 3) / 4; i += 1024) cnt32[i] = 0u;

    // ---- phase 1: argmax + valid flags (8 contiguous points / thread) ----
    const float* segb = seg + (size_t)b * 4 * NPTS;
    const float* lx   = lidar + (size_t)b * 5 * NPTS;
    const float* ly   = lx + NPTS;

    float px[8], py[8];
    int flags = 0, cnt = 0;
    const int n0 = tid * 8;
#pragma unroll
    for (int k = 0; k < 8; ++k) {
        const int n = n0 + k;
        float v0 = segb[n];
        float v1 = segb[NPTS + n];
        float v2 = segb[2 * NPTS + n];
        float v3 = segb[3 * NPTS + n];
        int bi = 0; float bv = v0;
        if (v1 > bv) { bv = v1; bi = 1; }
        if (v2 > bv) { bv = v2; bi = 2; }
        if (v3 > bv) { bv = v3; bi = 3; }
        px[k] = lx[n];
        py[k] = ly[n];
        if (bi == cls) { flags |= (1 << k); ++cnt; }
    }

    // ---- stable block scan of per-thread counts ----
    int v = cnt;
    for (int off = 1; off < 64; off <<= 1) {
        int nv = __shfl_up(v, off, 64);
        if (lane >= off) v += nv;
    }
    if (lane == 63) waveTot[wv] = v;
    __syncthreads();
    if (wv == 0) {
        int t = (lane < 16) ? waveTot[lane] : 0;
        for (int off = 1; off < 16; off <<= 1) {
            int nt = __shfl_up(t, off, 64);
            if (lane >= off) t += nt;
        }
        if (lane < 16) waveTot[lane] = t;
    }
    __syncthreads();

    int M = waveTot[15];
    if (M > CAP) M = CAP;
    const int rank0 = ((wv == 0) ? 0 : waveTot[wv - 1]) + v - cnt;
    int base = rank0;
#pragma unroll
    for (int k = 0; k < 8; ++k) {
        if (flags & (1 << k)) {
            if (base < CAP) {
                xy[base] = make_float2(px[k], py[k]);
                float fx = floorf((px[k] + GORG) * GINV);
                fx = fminf(fmaxf(fx, 0.0f), GMAXC);
                float fy = floorf((py[k] + GORG) * GINV);
                fy = fminf(fmaxf(fy, 0.0f), GMAXC);
                cellA[base] = (unsigned short)(((int)fy << 8) | (int)fx);
            }
            ++base;
        }
    }
    __syncthreads();

    // ---- phase 2: single-wave tiled greedy NMS with coord-grid ----
    if (wv == 0) {
        const int ntiles = (M + 63) >> 6;
        const int packSent = (55 << 8) | 55;

        // tile 0 state (coords + packed cell) in registers
        float qx = 3.0e38f, qy = 3.0e38f;
        int cc = packSent;
        if (lane < M) {
            float2 q = xy[lane]; qx = q.x; qy = q.y;
            cc = cellA[lane];
        }

        for (int t = 0; t < ntiles; ++t) {
            const int ts = t << 6;

            // -- prefetch next tile's coords + cell (independent reads) --
            float qxN = 3.0e38f, qyN = 3.0e38f;
            int ccN = packSent;
            {
                const int p2 = ts + 64 + lane;
                if (p2 < M) {
                    float2 q = xy[p2]; qxN = q.x; qyN = q.y;
                    ccN = cellA[p2];
                }
            }

            // -- slot addresses from register-resident packed cell --
            const int cx = cc & 0xFF, cy = cc >> 8;
            const int cxm = (cx > 0) ? cx - 1 : 0;
            const int cxp = (cx < GW - 1) ? cx + 1 : GW - 1;
            const int rm  = ((cy > 0) ? cy - 1 : 0) * GW;
            const int r0  = cy * GW;
            const int rp  = ((cy < GW - 1) ? cy + 1 : GW - 1) * GW;
            const int cLin = r0 + cx;                 // own cell (for insert)
            const int c9[9] = { rm + cxm, rm + cx, rm + cxp,
                                r0 + cxm, cLin,    r0 + cxp,
                                rp + cxm, rp + cx, rp + cxp };

            // -- 36 scattered b64 slot reads + d2 + min tree --
            float mm = 1.0e30f;
#pragma unroll
            for (int i = 0; i < 9; ++i) {
                const int sb = c9[i] * 4;
                const float2 s0 = gslot[sb];
                const float2 s1 = gslot[sb + 1];
                const float2 s2r = gslot[sb + 2];
                const float2 s3 = gslot[sb + 3];
                float dx, dy;
                dx = qx - s0.x; dy = qy - s0.y; const float e0 = dx * dx + dy * dy;
                dx = qx - s1.x; dy = qy - s1.y; const float e1 = dx * dx + dy * dy;
                dx = qx - s2r.x; dy = qy - s2r.y; const float e2 = dx * dx + dy * dy;
                dx = qx - s3.x; dy = qy - s3.y; const float e3 = dx * dx + dy * dy;
                const float cm = fminf(fminf(e0, e1), fminf(e2, e3));
                mm = fminf(mm, cm);
            }
            const bool sup = (mm <= R2C);

            // -- lean serial greedy resolve (uniform scalar loop) --
            int cntT = M - ts; if (cntT > 64) cntT = 64;
            const unsigned long long tm =
                (cntT >= 64) ? ~0ull : ((1ull << cntT) - 1ull);
            unsigned long long alive = __ballot(!sup) & tm;
            unsigned long long keepm = 0ull;
            while (alive) {
                const int l = __builtin_ctzll(alive);
                const float xl = __int_as_float(
                    __builtin_amdgcn_readlane(__float_as_int(qx), l));
                const float yl = __int_as_float(
                    __builtin_amdgcn_readlane(__float_as_int(qy), l));
                const float dx = qx - xl;
                const float dy = qy - yl;
                unsigned long long b2 = __ballot((dx * dx + dy * dy) <= R2C);
                keepm |= (1ull << l);
                alive &= ~b2;   // clears l (d2=0) and in-radius later points
            }
            if (lane == 0) keptW[t] = keepm;

            // -- insert kept points (own coords) into grid --
            if ((keepm >> lane) & 1ull) {
                const unsigned sh = 8u * (unsigned)(cLin & 3);
                unsigned old = atomicAdd(&cnt32[cLin >> 2], 1u << sh);
                unsigned mc = (old >> sh) & 0xFFu;
                if (mc < 4u) gslot[cLin * 4 + (int)mc] = make_float2(qx, qy);
            }

            // -- advance pipeline state --
            qx = qxN; qy = qyN; cc = ccN;
        }
    }
    __syncthreads();

    // ---- phase 3: scatter own kept points from registers ----
    int j = rank0;
#pragma unroll
    for (int k = 0; k < 8; ++k) {
        if (flags & (1 << k)) {
            if (j < M && ((keptW[j >> 6] >> (j & 63)) & 1ull)) {
                const int n = n0 + k;
                out0[2 * n]     = px[k];
                out0[2 * n + 1] = py[k];
                out1[n]         = 1.0f;
            }
            ++j;
        }
    }
}

extern "C" void kernel_launch(void* const* d_in, const int* in_sizes, int n_in,
                              void* d_out, int out_size, void* d_ws, size_t ws_size,
                              hipStream_t stream) {
    const float* seg   = (const float*)d_in[0];   // [4,4,64,128] f32
    const float* lidar = (const float*)d_in[1];   // [4,5,64,128] f32
    float* out = (float*)d_out;
    radius_nms_kernel<<<dim3(12), dim3(1024), 0, stream>>>(seg, lidar, out);
}